// Round 16
// baseline (464.447 us; speedup 1.0000x reference)
//
#include <hip/hip_runtime.h>
#include <hip/hip_bf16.h>

#define E_ 8
#define H_ 2048
#define I_ 5632
#define B_ 1024
#define K_ 2
#define NROWS (B_*K_)

#define BM 128
#define BN 64
#define BK 64
#define MAXT 24           // sum_e ceil(cnt_e/128) <= 16 + 8
#define NKG (H_/BK)       // 32  (gate/up K-phases)
#define NKD (I_/BK)       // 88  (down K-phases)
#define NYG (I_/BN)       // 88  (gate/up N-panels)
#define NYD (H_/BN)       // 32  (down N-panels)

typedef __attribute__((ext_vector_type(8))) __bf16 bf16x8;
typedef __attribute__((ext_vector_type(4))) float f32x4;

union BF4 { __bf16 b[4]; uint2 q; };
union BF8 { __bf16 b[8]; uint4 q; };

__device__ __forceinline__ void gld_lds16(const void* g, void* l) {
  __builtin_amdgcn_global_load_lds(
      (const __attribute__((address_space(1))) void*)g,
      (__attribute__((address_space(3))) void*)l, 16, 0, 0);
}

#define GLOAD4(dst, ptr) asm volatile("global_load_dwordx4 %0, %1, off" : "=v"(dst) : "v"(ptr))
#define WAITV(N) do { asm volatile("s_waitcnt vmcnt(" #N ")" ::: "memory"); __builtin_amdgcn_sched_barrier(0); } while(0)
#define WAITL()  do { asm volatile("s_waitcnt lgkmcnt(0)" ::: "memory"); __builtin_amdgcn_sched_barrier(0); } while(0)
#define BAR()    __builtin_amdgcn_s_barrier()

#define MSK(c) (((c)&7) ^ (((c)>>2)&7))   // R8-verified bank-spread swizzle

// ---------------- phase 0: x (f32) -> xb (bf16) ----------------
__global__ void cvtx_kernel(const float* __restrict__ x, __bf16* __restrict__ xb) {
  int i = (blockIdx.x * 256 + threadIdx.x) * 8;
  float4 a = *(const float4*)(x + i);
  float4 b = *(const float4*)(x + i + 4);
  BF8 r;
  r.b[0] = (__bf16)a.x; r.b[1] = (__bf16)a.y; r.b[2] = (__bf16)a.z; r.b[3] = (__bf16)a.w;
  r.b[4] = (__bf16)b.x; r.b[5] = (__bf16)b.y; r.b[6] = (__bf16)b.z; r.b[7] = (__bf16)b.w;
  *(uint4*)(xb + i) = r.q;
}

// ---------------- phase 1: routing + dense tile list ----------------
__global__ void route_kernel(const int* __restrict__ ids,
                             int* __restrict__ counts, int* __restrict__ offsets,
                             int* __restrict__ tlist, int* __restrict__ row_of,
                             int* __restrict__ tile_e, int* __restrict__ tile_m) {
  __shared__ int sc[E_], sp[E_], so[E_];
  int t = threadIdx.x;
  if (t < E_) { sc[t] = 0; sp[t] = 0; }
  __syncthreads();
  for (int idx = t; idx < NROWS; idx += 256) atomicAdd(&sc[ids[idx]], 1);
  __syncthreads();
  if (t == 0) {
    int acc = 0;
    for (int e = 0; e < E_; ++e) { so[e] = acc; acc += sc[e]; }
    int nt = 0;
    for (int e = 0; e < E_; ++e)
      for (int m0 = 0; m0 < sc[e]; m0 += BM) { tile_e[nt] = e; tile_m[nt] = m0; ++nt; }
    for (; nt < MAXT; ++nt) { tile_e[nt] = 0; tile_m[nt] = 0x7FFFFFFF; }
  }
  __syncthreads();
  for (int idx = t; idx < NROWS; idx += 256) {
    int e = ids[idx];
    int slot = atomicAdd(&sp[e], 1);
    int row = so[e] + slot;
    tlist[row] = idx / K_;
    row_of[idx] = row;
  }
  if (t < E_) { counts[t] = sc[t]; offsets[t] = so[t]; }
}

// =================================================================
// Shared GEMM body (the R8-proven down-kernel structure):
// 128x64 tile, BK=64, 4 waves, 48 KB LDS (A dbuf 2x16K + B dbuf 2x8K)
// -> 3 blocks/CU. Counted vmcnt: steady 8 outstanding (PF:4 + GLDA:4),
// one barrier per k-step. EPI is a per-kernel epilogue macro.
// =================================================================
#define GEMM_BODY(APTR, AIDX_TLIST, BPTR, KDIM, NDIM, NK, EPI)                \
  extern __shared__ char smem[];                                              \
  char* As0 = smem;                                                           \
  char* As1 = smem + 16384;                                                   \
  char* Bs0 = smem + 32768;                                                   \
  char* Bs1 = smem + 40960;                                                   \
  const int tid  = threadIdx.x;                                               \
  const int lane = tid & 63;                                                  \
  const int wave = tid >> 6;                                                  \
  const int wr = (wave >> 1) * 64;                                            \
  const int wc = (wave & 1) * 32;                                             \
  const __bf16* asrc0; const __bf16* asrc1; const __bf16* asrc2;              \
  const __bf16* asrc3;                                                        \
  int ad0, ad1, ad2, ad3;                                                     \
  {                                                                           \
    const __bf16* s[4]; int d[4];                                             \
    _Pragma("unroll")                                                         \
    for (int i = 0; i < 4; ++i) {                                             \
      int f = i*256 + tid;                                                    \
      int r = f >> 3, cs = f & 7;                                             \
      int rr = m0 + r; if (rr >= cnt) rr = cnt - 1;                           \
      size_t arow = AIDX_TLIST;                                               \
      s[i] = (APTR) + arow * (KDIM) + ((cs ^ (r & 7)) << 3);                  \
      d[i] = f * 16;                                                          \
    }                                                                         \
    asrc0=s[0]; asrc1=s[1]; asrc2=s[2]; asrc3=s[3];                           \
    ad0=d[0]; ad1=d[1]; ad2=d[2]; ad3=d[3];                                   \
  }                                                                           \
  const int cq = tid & 15;                                                    \
  const int kb = (tid >> 4) * 4;                                              \
  const float* pd0 = (BPTR) + (size_t)(kb + 0)*(NDIM) + n0 + 4*cq;            \
  const float* pd1 = (BPTR) + (size_t)(kb + 1)*(NDIM) + n0 + 4*cq;            \
  const float* pd2 = (BPTR) + (size_t)(kb + 2)*(NDIM) + n0 + 4*cq;            \
  const float* pd3 = (BPTR) + (size_t)(kb + 3)*(NDIM) + n0 + 4*cq;            \
  const int slot = kb >> 3;                                                   \
  const int half = (kb & 4) << 1;                                             \
  int bw0, bw1, bw2, bw3;                                                     \
  {                                                                           \
    int b[4];                                                                 \
    _Pragma("unroll")                                                         \
    for (int i = 0; i < 4; ++i) {                                             \
      int c = 4*cq + i;                                                       \
      b[i] = c*128 + ((slot ^ MSK(c)) << 4) + half;                           \
    }                                                                         \
    bw0=b[0]; bw1=b[1]; bw2=b[2]; bw3=b[3];                                   \
  }                                                                           \
  f32x4 vdA_0,vdA_1,vdA_2,vdA_3;                                              \
  f32x4 vdB_0,vdB_1,vdB_2,vdB_3;                                              \
  f32x4 acc[4][2];                                                            \
  _Pragma("unroll")                                                           \
  for (int i = 0; i < 4; ++i)                                                 \
    _Pragma("unroll")                                                         \
    for (int j = 0; j < 2; ++j) acc[i][j] = (f32x4){0.f,0.f,0.f,0.f};         \
  auto COMPUTE = [&](const char* Ab, const char* Bb) {                        \
    __builtin_amdgcn_s_setprio(1);                                            \
    _Pragma("unroll")                                                         \
    for (int kk = 0; kk < 2; ++kk) {                                          \
      const int ks = kk*4 + (lane >> 4);                                      \
      const int r0 = wr + (lane & 15);                                        \
      const int swa = (ks ^ (r0 & 7)) << 4;                                   \
      bf16x8 a0 = *(const bf16x8*)(Ab + (r0 +  0)*128 + swa);                 \
      bf16x8 a1 = *(const bf16x8*)(Ab + (r0 + 16)*128 + swa);                 \
      bf16x8 a2 = *(const bf16x8*)(Ab + (r0 + 32)*128 + swa);                 \
      bf16x8 a3 = *(const bf16x8*)(Ab + (r0 + 48)*128 + swa);                 \
      const int c0 = wc + (lane & 15);                                        \
      const int swb0 = (ks ^ MSK(c0)) << 4;                                   \
      const int swb1 = swb0 ^ (4 << 4);                                       \
      bf16x8 b0 = *(const bf16x8*)(Bb + c0*128 + swb0);                       \
      bf16x8 b1 = *(const bf16x8*)(Bb + (c0+16)*128 + swb1);                  \
      acc[0][0] = __builtin_amdgcn_mfma_f32_16x16x32_bf16(a0, b0, acc[0][0], 0,0,0); \
      acc[1][0] = __builtin_amdgcn_mfma_f32_16x16x32_bf16(a1, b0, acc[1][0], 0,0,0); \
      acc[2][0] = __builtin_amdgcn_mfma_f32_16x16x32_bf16(a2, b0, acc[2][0], 0,0,0); \
      acc[3][0] = __builtin_amdgcn_mfma_f32_16x16x32_bf16(a3, b0, acc[3][0], 0,0,0); \
      acc[0][1] = __builtin_amdgcn_mfma_f32_16x16x32_bf16(a0, b1, acc[0][1], 0,0,0); \
      acc[1][1] = __builtin_amdgcn_mfma_f32_16x16x32_bf16(a1, b1, acc[1][1], 0,0,0); \
      acc[2][1] = __builtin_amdgcn_mfma_f32_16x16x32_bf16(a2, b1, acc[2][1], 0,0,0); \
      acc[3][1] = __builtin_amdgcn_mfma_f32_16x16x32_bf16(a3, b1, acc[3][1], 0,0,0); \
    }                                                                         \
    __builtin_amdgcn_s_setprio(0);                                            \
  };                                                                          \
  auto PF = [&](int kpf) {                                                    \
    size_t o_ = (size_t)kpf*(size_t)BK*(size_t)(NDIM);                        \
    GLOAD4(vdA_0, pd0+o_); GLOAD4(vdA_1, pd1+o_);                             \
    GLOAD4(vdA_2, pd2+o_); GLOAD4(vdA_3, pd3+o_);                             \
  };                                                                          \
  auto PFB = [&](int kpf) {                                                   \
    size_t o_ = (size_t)kpf*(size_t)BK*(size_t)(NDIM);                        \
    GLOAD4(vdB_0, pd0+o_); GLOAD4(vdB_1, pd1+o_);                             \
    GLOAD4(vdB_2, pd2+o_); GLOAD4(vdB_3, pd3+o_);                             \
  };                                                                          \
  auto CVWA = [&](char* BB) {                                                 \
    BF4 p0_, p1_, p2_, p3_;                                                   \
    p0_.b[0]=(__bf16)vdA_0[0]; p0_.b[1]=(__bf16)vdA_1[0]; p0_.b[2]=(__bf16)vdA_2[0]; p0_.b[3]=(__bf16)vdA_3[0]; \
    p1_.b[0]=(__bf16)vdA_0[1]; p1_.b[1]=(__bf16)vdA_1[1]; p1_.b[2]=(__bf16)vdA_2[1]; p1_.b[3]=(__bf16)vdA_3[1]; \
    p2_.b[0]=(__bf16)vdA_0[2]; p2_.b[1]=(__bf16)vdA_1[2]; p2_.b[2]=(__bf16)vdA_2[2]; p2_.b[3]=(__bf16)vdA_3[2]; \
    p3_.b[0]=(__bf16)vdA_0[3]; p3_.b[1]=(__bf16)vdA_1[3]; p3_.b[2]=(__bf16)vdA_2[3]; p3_.b[3]=(__bf16)vdA_3[3]; \
    *(uint2*)(BB+bw0) = p0_.q; *(uint2*)(BB+bw1) = p1_.q;                     \
    *(uint2*)(BB+bw2) = p2_.q; *(uint2*)(BB+bw3) = p3_.q;                     \
  };                                                                          \
  auto CVWB = [&](char* BB) {                                                 \
    BF4 p0_, p1_, p2_, p3_;                                                   \
    p0_.b[0]=(__bf16)vdB_0[0]; p0_.b[1]=(__bf16)vdB_1[0]; p0_.b[2]=(__bf16)vdB_2[0]; p0_.b[3]=(__bf16)vdB_3[0]; \
    p1_.b[0]=(__bf16)vdB_0[1]; p1_.b[1]=(__bf16)vdB_1[1]; p1_.b[2]=(__bf16)vdB_2[1]; p1_.b[3]=(__bf16)vdB_3[1]; \
    p2_.b[0]=(__bf16)vdB_0[2]; p2_.b[1]=(__bf16)vdB_1[2]; p2_.b[2]=(__bf16)vdB_2[2]; p2_.b[3]=(__bf16)vdB_3[2]; \
    p3_.b[0]=(__bf16)vdB_0[3]; p3_.b[1]=(__bf16)vdB_1[3]; p3_.b[2]=(__bf16)vdB_2[3]; p3_.b[3]=(__bf16)vdB_3[3]; \
    *(uint2*)(BB+bw0) = p0_.q; *(uint2*)(BB+bw1) = p1_.q;                     \
    *(uint2*)(BB+bw2) = p2_.q; *(uint2*)(BB+bw3) = p3_.q;                     \
  };                                                                          \
  auto GLDA = [&](char* DST, int kpf) {                                       \
    size_t k_ = (size_t)kpf*(size_t)BK;                                       \
    gld_lds16(asrc0 + k_, DST+ad0); gld_lds16(asrc1 + k_, DST+ad1);           \
    gld_lds16(asrc2 + k_, DST+ad2); gld_lds16(asrc3 + k_, DST+ad3);           \
  };                                                                          \
  PF(0);                                                                      \
  GLDA(As0, 0);                                                               \
  WAITV(4);                                                                   \
  CVWA(Bs0);                                                                  \
  PFB(1);                                                                     \
  GLDA(As1, 1);                                                               \
  WAITV(8);                                                                   \
  WAITL();                                                                    \
  BAR();                                                                      \
  _Pragma("unroll 1")                                                         \
  for (int kt = 0; kt < (NK); kt += 2) {                                      \
    {                                                                         \
      int kpf = kt + 2; if (kpf > (NK)-1) kpf = (NK)-1;                       \
      PF(kpf);                                                                \
      COMPUTE(As0, Bs0);                                                      \
      WAITV(8);                                                               \
      CVWB(Bs1);                                                              \
      WAITV(4);                                                               \
      WAITL();                                                                \
      BAR();                                                                  \
      GLDA(As0, kpf);                                                         \
    }                                                                         \
    {                                                                         \
      int kpf = kt + 3; if (kpf > (NK)-1) kpf = (NK)-1;                       \
      PFB(kpf);                                                               \
      COMPUTE(As1, Bs1);                                                      \
      WAITV(8);                                                               \
      CVWA(Bs0);                                                              \
      WAITV(4);                                                               \
      WAITL();                                                                \
      BAR();                                                                  \
      GLDA(As1, kpf);                                                         \
    }                                                                         \
  }                                                                           \
  WAITV(0);                                                                   \
  WAITL();                                                                    \
  const int rsub = (lane >> 4) * 4;                                           \
  const int csub = lane & 15;                                                 \
  _Pragma("unroll")                                                           \
  for (int mi = 0; mi < 4; ++mi)                                              \
    _Pragma("unroll")                                                         \
    for (int j = 0; j < 4; ++j) {                                             \
      int rl = wr + mi*16 + rsub + j;                                         \
      if (m0 + rl < cnt) {                                                    \
        _Pragma("unroll")                                                     \
        for (int cg = 0; cg < 2; ++cg) {                                      \
          float v_ = acc[mi][cg][j];                                          \
          int col_ = n0 + wc + csub + cg*16;                                  \
          size_t row_ = (size_t)(off + m0 + rl);                              \
          EPI;                                                                \
        }                                                                     \
      }                                                                       \
    }

// ---------------- phase 2a: gate GEMM -> gbuf (bf16) ----------------
__global__ __launch_bounds__(256, 3) void gate_kernel(
    const __bf16* __restrict__ xb, const float* __restrict__ gw,
    const int* __restrict__ counts, const int* __restrict__ offsets,
    const int* __restrict__ tlist, const int* __restrict__ tile_e,
    const int* __restrict__ tile_m, __bf16* __restrict__ gbuf)
{
  const int id = blockIdx.x;                  // [0, 2112)
  const int w  = (id & 7) * 264 + (id >> 3);  // XCD chunking
  const int tt = w % MAXT;
  const int ny = w / MAXT;                    // [0, 88)
  const int e  = tile_e[tt];
  const int m0 = tile_m[tt];
  const int cnt = counts[e];
  if (m0 >= cnt) return;
  const int off = offsets[e];
  const int n0 = ny * BN;
  const float* bsrc = gw + (size_t)e*H_*I_;
  GEMM_BODY(xb, (size_t)tlist[off + rr], bsrc, H_, I_, NKG,
            gbuf[row_ * I_ + col_] = (__bf16)v_)
}

// ---------------- phase 2b: up GEMM + fused SiLU(g)*u -> act ----------------
__global__ __launch_bounds__(256, 3) void up_kernel(
    const __bf16* __restrict__ xb, const float* __restrict__ uw,
    const int* __restrict__ counts, const int* __restrict__ offsets,
    const int* __restrict__ tlist, const int* __restrict__ tile_e,
    const int* __restrict__ tile_m, const __bf16* __restrict__ gbuf,
    __bf16* __restrict__ act)
{
  const int id = blockIdx.x;                  // [0, 2112)
  const int w  = (id & 7) * 264 + (id >> 3);
  const int tt = w % MAXT;
  const int ny = w / MAXT;
  const int e  = tile_e[tt];
  const int m0 = tile_m[tt];
  const int cnt = counts[e];
  if (m0 >= cnt) return;
  const int off = offsets[e];
  const int n0 = ny * BN;
  const float* bsrc = uw + (size_t)e*H_*I_;
  GEMM_BODY(xb, (size_t)tlist[off + rr], bsrc, H_, I_, NKG,
            { float g_ = (float)gbuf[row_ * I_ + col_];
              float sg_ = g_ / (1.0f + __expf(-g_));
              act[row_ * I_ + col_] = (__bf16)(sg_ * v_); })
}

// ---------------- phase 3: down GEMM -> rowbuf (f32) ----------------
__global__ __launch_bounds__(256, 3) void down_kernel(
    const __bf16* __restrict__ act, const float* __restrict__ dw,
    const int* __restrict__ counts, const int* __restrict__ offsets,
    const int* __restrict__ tile_e, const int* __restrict__ tile_m,
    float* __restrict__ rowbuf)
{
  const int id = blockIdx.x;                  // [0, 768)
  const int w  = (id & 7) * 96 + (id >> 3);   // 768 = 8*96
  const int tt = w % MAXT;
  const int ny = w / MAXT;                    // [0, 32)
  const int e  = tile_e[tt];
  const int m0 = tile_m[tt];
  const int cnt = counts[e];
  if (m0 >= cnt) return;
  const int off = offsets[e];
  const int n0 = ny * BN;
  const float* bsrc = dw + (size_t)e*I_*H_;
  GEMM_BODY(act, (size_t)(off + rr), bsrc, I_, H_, NKD,
            rowbuf[row_ * H_ + col_] = v_)
}

// ---------------- phase 4: weighted combine ----------------
__global__ void combine_kernel(const float* __restrict__ ew, const int* __restrict__ row_of,
                               const float* __restrict__ rowbuf, float* __restrict__ out) {
  int idx = blockIdx.x * 256 + threadIdx.x;   // over B_*H_/4
  int t  = idx >> 9;                          // H_/4 = 512
  int h4 = idx & 511;
  float w0 = ew[t*2+0], w1 = ew[t*2+1];
  int r0 = row_of[t*2+0], r1 = row_of[t*2+1];
  float4 a = *(const float4*)(rowbuf + (size_t)r0*H_ + h4*4);
  float4 b = *(const float4*)(rowbuf + (size_t)r1*H_ + h4*4);
  float4 o;
  o.x = w0*a.x + w1*b.x; o.y = w0*a.y + w1*b.y;
  o.z = w0*a.z + w1*b.z; o.w = w0*a.w + w1*b.w;
  *(float4*)(out + (size_t)idx*4) = o;
}

extern "C" void kernel_launch(void* const* d_in, const int* in_sizes, int n_in,
                              void* d_out, int out_size, void* d_ws, size_t ws_size,
                              hipStream_t stream) {
  const float* x   = (const float*)d_in[0];
  const int*   ids = (const int*)d_in[1];
  const float* ew  = (const float*)d_in[2];
  const float* gw  = (const float*)d_in[3];
  const float* uw  = (const float*)d_in[4];
  const float* dwn = (const float*)d_in[5];
  float* out = (float*)d_out;

  char* ws = (char*)d_ws;
  int* counts  = (int*)ws;          // 8
  int* offsets = counts + 8;        // 8
  int* tlist   = offsets + 8;       // NROWS
  int* row_of  = tlist + NROWS;     // NROWS
  int* tile_e  = row_of + NROWS;    // MAXT
  int* tile_m  = tile_e + MAXT;     // MAXT
  size_t o = 32768;
  __bf16* xb    = (__bf16*)(ws + o);                 o += (size_t)B_*H_*2;
  __bf16* gbuf  = (__bf16*)(ws + o);                 o += (size_t)NROWS*I_*2;
  __bf16* act   = (__bf16*)(ws + o);                 o += (size_t)NROWS*I_*2;
  float*  rowbuf = (float*)(ws + o);

  hipFuncSetAttribute(reinterpret_cast<const void*>(&gate_kernel),
                      hipFuncAttributeMaxDynamicSharedMemorySize, 49152);
  hipFuncSetAttribute(reinterpret_cast<const void*>(&up_kernel),
                      hipFuncAttributeMaxDynamicSharedMemorySize, 49152);
  hipFuncSetAttribute(reinterpret_cast<const void*>(&down_kernel),
                      hipFuncAttributeMaxDynamicSharedMemorySize, 49152);

  cvtx_kernel<<<B_*H_/(256*8), 256, 0, stream>>>(x, xb);
  route_kernel<<<1, 256, 0, stream>>>(ids, counts, offsets, tlist, row_of, tile_e, tile_m);

  gate_kernel<<<MAXT*NYG, 256, 49152, stream>>>(xb, gw, counts, offsets, tlist,
                                                tile_e, tile_m, gbuf);
  up_kernel<<<MAXT*NYG, 256, 49152, stream>>>(xb, uw, counts, offsets, tlist,
                                              tile_e, tile_m, gbuf, act);
  down_kernel<<<MAXT*NYD, 256, 49152, stream>>>(act, dwn, counts, offsets,
                                                tile_e, tile_m, rowbuf);

  combine_kernel<<<(B_*H_/4)/256, 256, 0, stream>>>(ew, row_of, rowbuf, out);
}